// Round 7
// baseline (238.686 us; speedup 1.0000x reference)
//
#include <hip/hip_runtime.h>
#include <hip/hip_bf16.h>

typedef unsigned short u16;
typedef __attribute__((ext_vector_type(8))) short bf16x8;
typedef __attribute__((ext_vector_type(4))) float f32x4;
typedef __attribute__((ext_vector_type(8))) unsigned short u16x8;
typedef __attribute__((ext_vector_type(4))) unsigned int u32x4;

#define MFMA16(a, b, c) __builtin_amdgcn_mfma_f32_16x16x32_bf16((a), (b), (c), 0, 0, 0)

// LDS XOR swizzle for 128-byte rows: colbyte ^= SWZB(row). Gives uniform
// 8-lanes-per-16B-slot spread for both the permuted-K reads and V reads.
#define SWZB(row) ((((row) & 3) | ((((row) >> 3) & 1) << 2)) << 4)

__device__ __forceinline__ u16 f2b(float f) {
  union { float f; unsigned u; } c; c.f = f;
  unsigned u = c.u;
  u += 0x7FFFu + ((u >> 16) & 1u);   // RNE
  return (u16)(u >> 16);
}

// packed f32x2 -> bf16x2 (RNE), single VALU inst
__device__ __forceinline__ unsigned cvt_pk_bf16(float a, float b) {
  unsigned r;
  asm("v_cvt_pk_bf16_f32 %0, %1, %2" : "=v"(r) : "v"(a), "v"(b));
  return r;
}

__device__ __forceinline__ void gload_lds16(const u16* g, u16* l) {
  __builtin_amdgcn_global_load_lds(
      (__attribute__((address_space(1))) void*)(g),
      (__attribute__((address_space(3))) void*)(l),
      16, 0, 0);
}

// ---------------- f32 -> bf16 convert (x) ----------------
__global__ __launch_bounds__(256) void convert_f32_bf16(const float* __restrict__ in,
                                                        u16* __restrict__ out) {
  int i = (blockIdx.x * 256 + threadIdx.x) * 8;   // grid sized exactly
  float4 a = *(const float4*)&in[i];
  float4 b = *(const float4*)&in[i + 4];
  u16x8 o;
  o[0] = f2b(a.x); o[1] = f2b(a.y); o[2] = f2b(a.z); o[3] = f2b(a.w);
  o[4] = f2b(b.x); o[5] = f2b(b.y); o[6] = f2b(b.z); o[7] = f2b(b.w);
  *(u16x8*)&out[i] = o;
}

// ---------------- transpose + convert weights: Wt[n][k] = bf16(W[k][n]) ----------------
__global__ __launch_bounds__(256) void transpose_convert_w(
    const float* __restrict__ W0, const float* __restrict__ W1,
    const float* __restrict__ W2, const float* __restrict__ W3,
    u16* __restrict__ Wts) {
  __shared__ float t[32][33];
  int z = blockIdx.z;
  const float* W = (z == 0) ? W0 : (z == 1) ? W1 : (z == 2) ? W2 : W3;
  u16* Wt = Wts + (size_t)z * 1048576;
  int n0 = blockIdx.x * 32, k0 = blockIdx.y * 32;
  int tx = threadIdx.x, ty = threadIdx.y;
#pragma unroll
  for (int i = 0; i < 32; i += 8)
    t[ty + i][tx] = W[(size_t)(k0 + ty + i) * 1024 + n0 + tx];
  __syncthreads();
#pragma unroll
  for (int i = 0; i < 32; i += 8)
    Wt[(size_t)(n0 + ty + i) * 1024 + k0 + tx] = f2b(t[tx][ty + i]);
}

// ---------------- per-(b,h) V transpose: Vt[d][s] = V[s][d] (64 x 2048 per block) -----
__global__ __launch_bounds__(256) void transpose_v(const u16* __restrict__ V,
                                                   u16* __restrict__ Vt) {
  __shared__ u16 t[32][33];
  int bh = blockIdx.z;
  int s0 = blockIdx.x * 32, d0 = blockIdx.y * 32;
  const u16* Vb = V + (size_t)bh * 131072;
  u16* Vtb = Vt + (size_t)bh * 131072;
  int tx = threadIdx.x, ty = threadIdx.y;
#pragma unroll
  for (int i = 0; i < 32; i += 8)
    t[ty + i][tx] = Vb[(s0 + ty + i) * 64 + d0 + tx];
  __syncthreads();
#pragma unroll
  for (int i = 0; i < 32; i += 8)
    Vtb[(d0 + ty + i) * 2048 + s0 + tx] = t[tx][ty + i];
}

// ---------------- bf16 GEMM: out = A(8192x1024) * W(1024x1024) + bias ----------------
// Wt is n-major (transposed). m97 structure: 128x128 tile, BK=32, 4 waves 2x2,
// global_load_lds width 16, 16x16x32 MFMA, 4x4 acc per wave.
// z==0 (Q proj, bf16 out): folds 1/sqrt(DH) * log2(e) — softmax runs in exp2 domain.
template <bool F32OUT>
__global__ __launch_bounds__(256) void gemm_kernel(
    const u16* __restrict__ A, const u16* __restrict__ Wt0,
    const float* __restrict__ bias0, const float* __restrict__ bias1,
    const float* __restrict__ bias2,
    u16* __restrict__ outB, float* __restrict__ outF) {
  int z = blockIdx.z;
  const u16* Wt = Wt0 + (size_t)z * 1048576;
  const float* bias = (z == 0) ? bias0 : (z == 1) ? bias1 : bias2;
  u16* outb = outB + (size_t)z * 8388608;
  float oscale = (!F32OUT && z == 0) ? 0.125f * 1.44269504088896f : 1.0f;

  __shared__ u16 Alds[128 * 32];
  __shared__ u16 Blds[128 * 32];
  int tid = threadIdx.x;
  int lane = tid & 63, w = tid >> 6;
  int brow = blockIdx.x * 128;
  int bcol = blockIdx.y * 128;
  int wr = (w >> 1) * 64, wc = (w & 1) * 64;
  int r = lane & 15, half = lane >> 4;

  f32x4 acc[4][4] = {};
  int f0 = (w * 2 + 0) * 512 + lane * 8;   // flat bf16 index in the 128x32 tile
  int f1 = (w * 2 + 1) * 512 + lane * 8;
  const u16* Abase = A + (size_t)brow * 1024;
  const u16* Bbase = Wt + (size_t)bcol * 1024;

  for (int k0 = 0; k0 < 1024; k0 += 32) {
    gload_lds16(Abase + (size_t)(f0 >> 5) * 1024 + k0 + (f0 & 31), &Alds[(w * 2 + 0) * 512]);
    gload_lds16(Abase + (size_t)(f1 >> 5) * 1024 + k0 + (f1 & 31), &Alds[(w * 2 + 1) * 512]);
    gload_lds16(Bbase + (size_t)(f0 >> 5) * 1024 + k0 + (f0 & 31), &Blds[(w * 2 + 0) * 512]);
    gload_lds16(Bbase + (size_t)(f1 >> 5) * 1024 + k0 + (f1 & 31), &Blds[(w * 2 + 1) * 512]);
    __syncthreads();
    bf16x8 af[4], bf[4];
#pragma unroll
    for (int m = 0; m < 4; ++m)
      af[m] = *(const bf16x8*)&Alds[(wr + m * 16 + r) * 32 + half * 8];
#pragma unroll
    for (int n = 0; n < 4; ++n)
      bf[n] = *(const bf16x8*)&Blds[(wc + n * 16 + r) * 32 + half * 8];
#pragma unroll
    for (int m = 0; m < 4; ++m)
#pragma unroll
      for (int n = 0; n < 4; ++n)
        acc[m][n] = MFMA16(af[m], bf[n], acc[m][n]);
    __syncthreads();
  }
#pragma unroll
  for (int m = 0; m < 4; ++m) {
    int rowb = brow + wr + m * 16 + half * 4;
#pragma unroll
    for (int n = 0; n < 4; ++n) {
      int col = bcol + wc + n * 16 + r;
      float bv = bias[col];
#pragma unroll
      for (int j = 0; j < 4; ++j) {
        float v = (acc[m][n][j] + bv) * oscale;
        size_t idx = (size_t)(rowb + j) * 1024 + col;
        if (F32OUT) outF[idx] = v;
        else        outb[idx] = f2b(v);
      }
    }
  }
}

// ---------------- causal flash attention per (b,h): N=2048, D=64 ----------------
// 32 q-rows per wave (two 16-row groups A/B), 64-key tiles. Swapped-operand
// S^T = MFMA(K, Q) in exp2 domain; lane owns one q-row per group; permuted K
// rows make the lane's 16 P values exactly the PV B-fragment. All LDS read
// addresses hoisted to loop-invariant offsets (SWZB invariant under the
// +4/+32/+16-row deltas); staging via 4 incremented global pointers.
// Defer-max (THR=8): common path has ZERO cross-lane ops; l reduced at end.
__device__ __forceinline__ float fmax16(const f32x4 (&s)[2][2]) {
  float a0 = fmaxf(fmaxf(s[0][0][0], s[0][0][1]), fmaxf(s[0][0][2], s[0][0][3]));
  float a1 = fmaxf(fmaxf(s[0][1][0], s[0][1][1]), fmaxf(s[0][1][2], s[0][1][3]));
  float a2 = fmaxf(fmaxf(s[1][0][0], s[1][0][1]), fmaxf(s[1][0][2], s[1][0][3]));
  float a3 = fmaxf(fmaxf(s[1][1][0], s[1][1][1]), fmaxf(s[1][1][2], s[1][1][3]));
  return fmaxf(fmaxf(a0, a1), fmaxf(a2, a3));
}

__device__ __forceinline__ void softmax_tile(
    f32x4 (&sT)[2][2], int kb, int qmin, int r, int half,
    float& m_run, float& l_run, f32x4 (&om)[4], u32x4 (&pw)[2]) {
  if (kb + 63 > qmin) {                  // wave-uniform mask gate
    const int q = qmin + r;
#pragma unroll
    for (int c = 0; c < 2; ++c)
#pragma unroll
      for (int t = 0; t < 2; ++t)
#pragma unroll
        for (int j = 0; j < 4; ++j)
          if (kb + c * 32 + half * 8 + t * 4 + j > q) sT[c][t][j] = -1e30f;
  }
  const float mloc = fmax16(sT);
  if (__any(mloc > m_run + 8.0f)) {      // rare path: reduce + rescale
    float mr = fmaxf(mloc, __shfl_xor(mloc, 16));
    mr = fmaxf(mr, __shfl_xor(mr, 32));
    const float nm = fmaxf(m_run, mr);
    const float corr = __builtin_exp2f(m_run - nm);
    m_run = nm;
    l_run *= corr;
#pragma unroll
    for (int f = 0; f < 4; ++f)
#pragma unroll
      for (int j = 0; j < 4; ++j) om[f][j] *= corr;
  }
  const float mb = m_run;
  float ll = 0.f;
#pragma unroll
  for (int c = 0; c < 2; ++c)
#pragma unroll
    for (int t = 0; t < 2; ++t) {
      const float e0 = __builtin_exp2f(sT[c][t][0] - mb);
      const float e1 = __builtin_exp2f(sT[c][t][1] - mb);
      const float e2 = __builtin_exp2f(sT[c][t][2] - mb);
      const float e3 = __builtin_exp2f(sT[c][t][3] - mb);
      ll += (e0 + e1) + (e2 + e3);
      pw[c][t * 2 + 0] = cvt_pk_bf16(e0, e1);
      pw[c][t * 2 + 1] = cvt_pk_bf16(e2, e3);
    }
  l_run += ll;
}

__global__ __launch_bounds__(256, 4) void attn_kernel(
    const u16* __restrict__ Q, const u16* __restrict__ K,
    const u16* __restrict__ Vt, u16* __restrict__ Z) {
  __shared__ u16 Kl[2][4096];
  __shared__ u16 Vl[2][4096];
  // XCD-affinity: all q-blocks of a head on one XCD (round-robin linear%8).
  const int L = blockIdx.x;
  const int xcd = L & 7;
  const int i = L >> 3;
  const int bh = ((i >> 4) << 3) | xcd;
  const int x = i & 15;                  // q-block (128 rows each)
  const int tid = threadIdx.x;
  const int w = tid >> 6;
  const int lane = tid & 63;
  const int r = lane & 15, half = lane >> 4;
  const u16* Qb = Q + (size_t)bh * 131072;
  const u16* Kb = K + (size_t)bh * 131072;
  const u16* Vtb = Vt + (size_t)bh * 131072;
  u16* Zb = Z + (size_t)bh * 131072;

  const int qw = x * 128 + w * 32;       // wave's 32-row base
  const int nt = 2 * x + 2;

  // Q fragments (two 16-row groups)
  const bf16x8 qA0 = *(const bf16x8*)&Qb[(qw + r) * 64 + half * 8];
  const bf16x8 qA1 = *(const bf16x8*)&Qb[(qw + r) * 64 + 32 + half * 8];
  const bf16x8 qB0 = *(const bf16x8*)&Qb[(qw + 16 + r) * 64 + half * 8];
  const bf16x8 qB1 = *(const bf16x8*)&Qb[(qw + 16 + r) * 64 + 32 + half * 8];

  // hoisted swizzled LDS byte offsets (loop-invariant; +512/+4096/+2048
  // deltas preserve SWZB so they fold into ds_read immediates)
  const int krow00 = ((r >> 2) << 3) | (r & 3);
  const int aK0 = krow00 * 128 + ((half * 16) ^ SWZB(krow00));
  const int aK1 = krow00 * 128 + ((64 + half * 16) ^ SWZB(krow00));
  const int aV0 = r * 128 + ((half * 16) ^ SWZB(r));
  const int aV1 = r * 128 + ((64 + half * 16) ^ SWZB(r));

  // staging pointers (incremented per tile; dest LDS fixed per thread)
  const int row0 = tid >> 3, row1 = row0 + 32;
  const int cb0 = (tid & 7) << 4;
  const u16* kg0 = Kb + (size_t)row0 * 64 + ((cb0 ^ SWZB(row0)) >> 1);
  const u16* kg1 = Kb + (size_t)row1 * 64 + ((cb0 ^ SWZB(row1)) >> 1);
  const u16* vg0 = Vtb + (size_t)row0 * 2048 + ((cb0 ^ SWZB(row0)) >> 1);
  const u16* vg1 = Vtb + (size_t)row1 * 2048 + ((cb0 ^ SWZB(row1)) >> 1);
  u16* kd0 = &Kl[0][0] + tid * 8;  u16* kd1 = kd0 + 2048;
  u16* vd0 = &Vl[0][0] + tid * 8;  u16* vd1 = vd0 + 2048;

  f32x4 omA[4] = {}, omB[4] = {};
  u32x4 pwA[2], pwB[2];
  float mA = -1e30f, mB = -1e30f, lA = 0.f, lB = 0.f;

  gload_lds16(kg0, kd0); gload_lds16(kg1, kd1);
  gload_lds16(vg0, vd0); gload_lds16(vg1, vd1);
  kg0 += 4096; kg1 += 4096; vg0 += 64; vg1 += 64;
  int curB = 0;

  for (int kt = 0; kt < nt; ++kt) {
    const int kb = kt * 64;
    __syncthreads();                     // drains staging + seals prev readers
    if (kt + 1 < nt) {
      const int nb = curB ^ 8192;
      gload_lds16(kg0, (u16*)((char*)kd0 + nb));
      gload_lds16(kg1, (u16*)((char*)kd1 + nb));
      gload_lds16(vg0, (u16*)((char*)vd0 + nb));
      gload_lds16(vg1, (u16*)((char*)vd1 + nb));
      kg0 += 4096; kg1 += 4096; vg0 += 64; vg1 += 64;
    }
    const char* Kc = (const char*)&Kl[0][0] + curB;
    const char* Vc = (const char*)&Vl[0][0] + curB;

    f32x4 sT[2][2];
    // ---- q-group A ----
    __builtin_amdgcn_s_setprio(1);
#pragma unroll
    for (int c = 0; c < 2; ++c)
#pragma unroll
      for (int t = 0; t < 2; ++t) {
        const bf16x8 kf0 = *(const bf16x8*)(Kc + aK0 + c * 4096 + t * 512);
        const bf16x8 kf1 = *(const bf16x8*)(Kc + aK1 + c * 4096 + t * 512);
        f32x4 z = {};
        z = MFMA16(kf0, qA0, z);
        z = MFMA16(kf1, qA1, z);
        sT[c][t] = z;
      }
    __builtin_amdgcn_s_setprio(0);
    softmax_tile(sT, kb, qw, r, half, mA, lA, omA, pwA);
    // ---- q-group B ----
    __builtin_amdgcn_s_setprio(1);
#pragma unroll
    for (int c = 0; c < 2; ++c)
#pragma unroll
      for (int t = 0; t < 2; ++t) {
        const bf16x8 kf0 = *(const bf16x8*)(Kc + aK0 + c * 4096 + t * 512);
        const bf16x8 kf1 = *(const bf16x8*)(Kc + aK1 + c * 4096 + t * 512);
        f32x4 z = {};
        z = MFMA16(kf0, qB0, z);
        z = MFMA16(kf1, qB1, z);
        sT[c][t] = z;
      }
    __builtin_amdgcn_s_setprio(0);
    softmax_tile(sT, kb, qw + 16, r, half, mB, lB, omB, pwB);
    // ---- PV (V frags shared across both groups) ----
    __builtin_amdgcn_s_setprio(1);
#pragma unroll
    for (int c = 0; c < 2; ++c) {
      const bf16x8 pa = __builtin_bit_cast(bf16x8, pwA[c]);
      const bf16x8 pb = __builtin_bit_cast(bf16x8, pwB[c]);
      const int av = c ? aV1 : aV0;
#pragma unroll
      for (int f = 0; f < 4; ++f) {
        const bf16x8 vf = *(const bf16x8*)(Vc + av + f * 2048);
        omA[f] = MFMA16(vf, pa, omA[f]);
        omB[f] = MFMA16(vf, pb, omB[f]);
      }
    }
    __builtin_amdgcn_s_setprio(0);
    curB ^= 8192;
  }

  // one cross-replica l-reduce per strip
  lA += __shfl_xor(lA, 16); lA += __shfl_xor(lA, 32);
  lB += __shfl_xor(lB, 16); lB += __shfl_xor(lB, 32);
  const float invA = 1.0f / lA;
  const float invB = 1.0f / lB;
  const int qa = qw + r, qb2 = qw + 16 + r;
#pragma unroll
  for (int f = 0; f < 4; ++f) {
    ushort4 sa, sb;
    sa.x = f2b(omA[f][0] * invA); sa.y = f2b(omA[f][1] * invA);
    sa.z = f2b(omA[f][2] * invA); sa.w = f2b(omA[f][3] * invA);
    sb.x = f2b(omB[f][0] * invB); sb.y = f2b(omB[f][1] * invB);
    sb.z = f2b(omB[f][2] * invB); sb.w = f2b(omB[f][3] * invB);
    *(ushort4*)&Zb[(size_t)qa * 64 + f * 16 + half * 4] = sa;
    *(ushort4*)&Zb[(size_t)qb2 * 64 + f * 16 + half * 4] = sb;
  }
}

extern "C" void kernel_launch(void* const* d_in, const int* in_sizes, int n_in,
                              void* d_out, int out_size, void* d_ws, size_t ws_size,
                              hipStream_t stream) {
  (void)in_sizes; (void)n_in; (void)out_size; (void)ws_size;
  const float* x  = (const float*)d_in[0];
  const float* Wq = (const float*)d_in[1];
  const float* bq = (const float*)d_in[2];
  const float* Wk = (const float*)d_in[3];
  const float* bk = (const float*)d_in[4];
  const float* Wv = (const float*)d_in[5];
  const float* bv = (const float*)d_in[6];
  const float* Wo = (const float*)d_in[7];
  const float* bo = (const float*)d_in[8];
  float* out = (float*)d_out;

  char* ws = (char*)d_ws;
  u16* xb  = (u16*)(ws);                  // 16 MB, reused as Z after attention
  u16* Wts = (u16*)(ws + 16777216);       // 4 x 2 MB (q,k,v,o; n-major bf16)
  u16* Qb  = (u16*)(ws + 25165824);       // 16 MB
  u16* Kb  = (u16*)(ws + 41943040);       // 16 MB
  u16* Vb  = (u16*)(ws + 58720256);       // 16 MB
  u16* Vtb = (u16*)(ws + 75497472);       // 16 MB  (total 92 MB)

  convert_f32_bf16<<<4096, 256, 0, stream>>>(x, xb);
  {
    dim3 g(32, 32, 4), b(32, 8);
    transpose_convert_w<<<g, b, 0, stream>>>(Wq, Wk, Wv, Wo, Wts);
  }
  {
    dim3 g(64, 8, 3), b(256);
    gemm_kernel<false><<<g, b, 0, stream>>>(xb, Wts, bq, bk, bv, Qb, nullptr);
  }
  {
    dim3 g(64, 2, 64), b(32, 8);
    transpose_v<<<g, b, 0, stream>>>(Vb, Vtb);
  }
  {
    dim3 g(1024), b(256);
    attn_kernel<<<g, b, 0, stream>>>(Qb, Kb, Vtb, xb /* Z */);
  }
  {
    dim3 g(64, 8, 1), b(256);
    gemm_kernel<true><<<g, b, 0, stream>>>(xb, Wts + 3 * 1048576, bo, bo, bo, Qb, out);
  }
}

// Round 8
// 199.667 us; speedup vs baseline: 1.1954x; 1.1954x over previous
//
#include <hip/hip_runtime.h>
#include <hip/hip_bf16.h>

typedef unsigned short u16;
typedef __attribute__((ext_vector_type(8))) short bf16x8;
typedef __attribute__((ext_vector_type(4))) float f32x4;
typedef __attribute__((ext_vector_type(8))) unsigned short u16x8;
typedef __attribute__((ext_vector_type(4))) unsigned int u32x4;

#define MFMA16(a, b, c) __builtin_amdgcn_mfma_f32_16x16x32_bf16((a), (b), (c), 0, 0, 0)

// LDS XOR swizzle for 128-byte rows: colbyte ^= SWZB(row). Gives uniform
// 8-lanes-per-16B-slot spread for both the permuted-K reads and V reads.
#define SWZB(row) ((((row) & 3) | ((((row) >> 3) & 1) << 2)) << 4)

__device__ __forceinline__ u16 f2b(float f) {
  union { float f; unsigned u; } c; c.f = f;
  unsigned u = c.u;
  u += 0x7FFFu + ((u >> 16) & 1u);   // RNE
  return (u16)(u >> 16);
}

// packed f32x2 -> bf16x2 (RNE), single VALU inst
__device__ __forceinline__ unsigned cvt_pk_bf16(float a, float b) {
  unsigned r;
  asm("v_cvt_pk_bf16_f32 %0, %1, %2" : "=v"(r) : "v"(a), "v"(b));
  return r;
}

__device__ __forceinline__ void gload_lds16(const u16* g, u16* l) {
  __builtin_amdgcn_global_load_lds(
      (__attribute__((address_space(1))) void*)(g),
      (__attribute__((address_space(3))) void*)(l),
      16, 0, 0);
}

// ---------------- f32 -> bf16 convert (x) ----------------
__global__ __launch_bounds__(256) void convert_f32_bf16(const float* __restrict__ in,
                                                        u16* __restrict__ out) {
  int i = (blockIdx.x * 256 + threadIdx.x) * 8;   // grid sized exactly
  float4 a = *(const float4*)&in[i];
  float4 b = *(const float4*)&in[i + 4];
  u16x8 o;
  o[0] = f2b(a.x); o[1] = f2b(a.y); o[2] = f2b(a.z); o[3] = f2b(a.w);
  o[4] = f2b(b.x); o[5] = f2b(b.y); o[6] = f2b(b.z); o[7] = f2b(b.w);
  *(u16x8*)&out[i] = o;
}

// ---------------- transpose + convert weights: Wt[n][k] = bf16(W[k][n]) ----------------
__global__ __launch_bounds__(256) void transpose_convert_w(
    const float* __restrict__ W0, const float* __restrict__ W1,
    const float* __restrict__ W2, const float* __restrict__ W3,
    u16* __restrict__ Wts) {
  __shared__ float t[32][33];
  int z = blockIdx.z;
  const float* W = (z == 0) ? W0 : (z == 1) ? W1 : (z == 2) ? W2 : W3;
  u16* Wt = Wts + (size_t)z * 1048576;
  int n0 = blockIdx.x * 32, k0 = blockIdx.y * 32;
  int tx = threadIdx.x, ty = threadIdx.y;
#pragma unroll
  for (int i = 0; i < 32; i += 8)
    t[ty + i][tx] = W[(size_t)(k0 + ty + i) * 1024 + n0 + tx];
  __syncthreads();
#pragma unroll
  for (int i = 0; i < 32; i += 8)
    Wt[(size_t)(n0 + ty + i) * 1024 + k0 + tx] = f2b(t[tx][ty + i]);
}

// ---------------- per-(b,h) V transpose: Vt[d][s] = V[s][d] (64 x 2048 per block) -----
__global__ __launch_bounds__(256) void transpose_v(const u16* __restrict__ V,
                                                   u16* __restrict__ Vt) {
  __shared__ u16 t[32][33];
  int bh = blockIdx.z;
  int s0 = blockIdx.x * 32, d0 = blockIdx.y * 32;
  const u16* Vb = V + (size_t)bh * 131072;
  u16* Vtb = Vt + (size_t)bh * 131072;
  int tx = threadIdx.x, ty = threadIdx.y;
#pragma unroll
  for (int i = 0; i < 32; i += 8)
    t[ty + i][tx] = Vb[(s0 + ty + i) * 64 + d0 + tx];
  __syncthreads();
#pragma unroll
  for (int i = 0; i < 32; i += 8)
    Vtb[(d0 + ty + i) * 2048 + s0 + tx] = t[tx][ty + i];
}

// ---------------- bf16 GEMM: out = A(8192x1024) * W(1024x1024) + bias ----------------
// Wt is n-major (transposed). m97 structure: 128x128 tile, BK=32, 4 waves 2x2,
// global_load_lds width 16, 16x16x32 MFMA, 4x4 acc per wave.
// z==0 (Q proj, bf16 out): folds 1/sqrt(DH) * log2(e) — softmax runs in exp2 domain.
template <bool F32OUT>
__global__ __launch_bounds__(256) void gemm_kernel(
    const u16* __restrict__ A, const u16* __restrict__ Wt0,
    const float* __restrict__ bias0, const float* __restrict__ bias1,
    const float* __restrict__ bias2,
    u16* __restrict__ outB, float* __restrict__ outF) {
  int z = blockIdx.z;
  const u16* Wt = Wt0 + (size_t)z * 1048576;
  const float* bias = (z == 0) ? bias0 : (z == 1) ? bias1 : bias2;
  u16* outb = outB + (size_t)z * 8388608;
  float oscale = (!F32OUT && z == 0) ? 0.125f * 1.44269504088896f : 1.0f;

  __shared__ u16 Alds[128 * 32];
  __shared__ u16 Blds[128 * 32];
  int tid = threadIdx.x;
  int lane = tid & 63, w = tid >> 6;
  int brow = blockIdx.x * 128;
  int bcol = blockIdx.y * 128;
  int wr = (w >> 1) * 64, wc = (w & 1) * 64;
  int r = lane & 15, half = lane >> 4;

  f32x4 acc[4][4] = {};
  int f0 = (w * 2 + 0) * 512 + lane * 8;   // flat bf16 index in the 128x32 tile
  int f1 = (w * 2 + 1) * 512 + lane * 8;
  const u16* Abase = A + (size_t)brow * 1024;
  const u16* Bbase = Wt + (size_t)bcol * 1024;

  for (int k0 = 0; k0 < 1024; k0 += 32) {
    gload_lds16(Abase + (size_t)(f0 >> 5) * 1024 + k0 + (f0 & 31), &Alds[(w * 2 + 0) * 512]);
    gload_lds16(Abase + (size_t)(f1 >> 5) * 1024 + k0 + (f1 & 31), &Alds[(w * 2 + 1) * 512]);
    gload_lds16(Bbase + (size_t)(f0 >> 5) * 1024 + k0 + (f0 & 31), &Blds[(w * 2 + 0) * 512]);
    gload_lds16(Bbase + (size_t)(f1 >> 5) * 1024 + k0 + (f1 & 31), &Blds[(w * 2 + 1) * 512]);
    __syncthreads();
    bf16x8 af[4], bf[4];
#pragma unroll
    for (int m = 0; m < 4; ++m)
      af[m] = *(const bf16x8*)&Alds[(wr + m * 16 + r) * 32 + half * 8];
#pragma unroll
    for (int n = 0; n < 4; ++n)
      bf[n] = *(const bf16x8*)&Blds[(wc + n * 16 + r) * 32 + half * 8];
#pragma unroll
    for (int m = 0; m < 4; ++m)
#pragma unroll
      for (int n = 0; n < 4; ++n)
        acc[m][n] = MFMA16(af[m], bf[n], acc[m][n]);
    __syncthreads();
  }
#pragma unroll
  for (int m = 0; m < 4; ++m) {
    int rowb = brow + wr + m * 16 + half * 4;
#pragma unroll
    for (int n = 0; n < 4; ++n) {
      int col = bcol + wc + n * 16 + r;
      float bv = bias[col];
#pragma unroll
      for (int j = 0; j < 4; ++j) {
        float v = (acc[m][n][j] + bv) * oscale;
        size_t idx = (size_t)(rowb + j) * 1024 + col;
        if (F32OUT) outF[idx] = v;
        else        outb[idx] = f2b(v);
      }
    }
  }
}

// ---------------- causal flash attention per (b,h): N=2048, D=64 ----------------
// 128-thread blocks: 2 waves x 32 q-rows = 64-row strip; block runs strip pair
// (x, 31-x) sequentially -> uniform 33 tiles/block (restores R6 balance) while
// keeping R7's 32-rows-per-wave overhead amortization. Swapped-operand
// S^T = MFMA(K, Q) in exp2 domain; permuted K rows make the lane's 16 P values
// exactly the PV B-fragment; defer-max common path has zero cross-lane ops.
__device__ __forceinline__ float fmax16(const f32x4 (&s)[2][2]) {
  float a0 = fmaxf(fmaxf(s[0][0][0], s[0][0][1]), fmaxf(s[0][0][2], s[0][0][3]));
  float a1 = fmaxf(fmaxf(s[0][1][0], s[0][1][1]), fmaxf(s[0][1][2], s[0][1][3]));
  float a2 = fmaxf(fmaxf(s[1][0][0], s[1][0][1]), fmaxf(s[1][0][2], s[1][0][3]));
  float a3 = fmaxf(fmaxf(s[1][1][0], s[1][1][1]), fmaxf(s[1][1][2], s[1][1][3]));
  return fmaxf(fmaxf(a0, a1), fmaxf(a2, a3));
}

__device__ __forceinline__ void softmax_tile(
    f32x4 (&sT)[2][2], int kb, int qmin, int r, int half,
    float& m_run, float& l_run, f32x4 (&om)[4], u32x4 (&pw)[2]) {
  if (kb + 63 > qmin) {                  // wave-uniform mask gate
    const int q = qmin + r;
#pragma unroll
    for (int c = 0; c < 2; ++c)
#pragma unroll
      for (int t = 0; t < 2; ++t)
#pragma unroll
        for (int j = 0; j < 4; ++j)
          if (kb + c * 32 + half * 8 + t * 4 + j > q) sT[c][t][j] = -1e30f;
  }
  const float mloc = fmax16(sT);
  if (__any(mloc > m_run + 8.0f)) {      // rare path: reduce + rescale
    float mr = fmaxf(mloc, __shfl_xor(mloc, 16));
    mr = fmaxf(mr, __shfl_xor(mr, 32));
    const float nm = fmaxf(m_run, mr);
    const float corr = __builtin_exp2f(m_run - nm);
    m_run = nm;
    l_run *= corr;
#pragma unroll
    for (int f = 0; f < 4; ++f)
#pragma unroll
      for (int j = 0; j < 4; ++j) om[f][j] *= corr;
  }
  const float mb = m_run;
  float ll = 0.f;
#pragma unroll
  for (int c = 0; c < 2; ++c)
#pragma unroll
    for (int t = 0; t < 2; ++t) {
      const float e0 = __builtin_exp2f(sT[c][t][0] - mb);
      const float e1 = __builtin_exp2f(sT[c][t][1] - mb);
      const float e2 = __builtin_exp2f(sT[c][t][2] - mb);
      const float e3 = __builtin_exp2f(sT[c][t][3] - mb);
      ll += (e0 + e1) + (e2 + e3);
      pw[c][t * 2 + 0] = cvt_pk_bf16(e0, e1);
      pw[c][t * 2 + 1] = cvt_pk_bf16(e2, e3);
    }
  l_run += ll;
}

__device__ __forceinline__ void attn_strip32(
    const u16* __restrict__ Qb, const u16* __restrict__ Kb,
    const u16* __restrict__ Vtb, u16* __restrict__ Zb,
    u16* Kl, u16* Vl, int qstrip, int nt, int tid) {
  const int lane = tid & 63;
  const int w = tid >> 6;                // 0..1
  const int r = lane & 15, half = lane >> 4;
  const int qw = qstrip + w * 32;        // wave's 32-row base

  const bf16x8 qA0 = *(const bf16x8*)&Qb[(qw + r) * 64 + half * 8];
  const bf16x8 qA1 = *(const bf16x8*)&Qb[(qw + r) * 64 + 32 + half * 8];
  const bf16x8 qB0 = *(const bf16x8*)&Qb[(qw + 16 + r) * 64 + half * 8];
  const bf16x8 qB1 = *(const bf16x8*)&Qb[(qw + 16 + r) * 64 + 32 + half * 8];

  // hoisted swizzled LDS read offsets (SWZB invariant under the c/t/f deltas)
  const int krow00 = ((r >> 2) << 3) | (r & 3);
  const int aK0 = krow00 * 128 + ((half * 16) ^ SWZB(krow00));
  const int aK1 = krow00 * 128 + ((64 + half * 16) ^ SWZB(krow00));
  const int aV0 = r * 128 + ((half * 16) ^ SWZB(r));
  const int aV1 = r * 128 + ((64 + half * 16) ^ SWZB(r));

  // staging: 128 threads cover rows 0..15 per instr; 4 instrs (+16 rows each,
  // SWZB invariant under +16) cover 64 rows for K and for V
  const int row0 = tid >> 3;             // 0..15
  const int cb0 = (tid & 7) << 4;
  const int sw = (cb0 ^ SWZB(row0)) >> 1;
  const u16* kg = Kb + row0 * 64 + sw;
  const u16* vg = Vtb + (size_t)row0 * 2048 + sw;
  u16* kd = Kl + tid * 8;
  u16* vd = Vl + tid * 8;

  f32x4 omA[4] = {}, omB[4] = {};
  u32x4 pwA[2], pwB[2];
  float mA = -1e30f, mB = -1e30f, lA = 0.f, lB = 0.f;

  __syncthreads();                       // seal previous readers of buf0
#pragma unroll
  for (int i = 0; i < 4; ++i) {
    gload_lds16(kg + 1024 * i, kd + 1024 * i);
    gload_lds16(vg + 32768 * i, vd + 1024 * i);
  }
  kg += 4096; vg += 64;
  int cur = 0;                           // u16 offset: {0, 4096}

  for (int kt = 0; kt < nt; ++kt) {
    const int kb = kt * 64;
    __syncthreads();                     // drains staging + seals prev readers
    if (kt + 1 < nt) {
      const int nb = cur ^ 4096;
#pragma unroll
      for (int i = 0; i < 4; ++i) {
        gload_lds16(kg + 1024 * i, kd + nb + 1024 * i);
        gload_lds16(vg + 32768 * i, vd + nb + 1024 * i);
      }
      kg += 4096; vg += 64;
    }
    const char* Kc = (const char*)(Kl + cur);
    const char* Vc = (const char*)(Vl + cur);

    f32x4 sT[2][2];
    // ---- q-group A ----
    __builtin_amdgcn_s_setprio(1);
#pragma unroll
    for (int c = 0; c < 2; ++c)
#pragma unroll
      for (int t = 0; t < 2; ++t) {
        const bf16x8 kf0 = *(const bf16x8*)(Kc + aK0 + c * 4096 + t * 512);
        const bf16x8 kf1 = *(const bf16x8*)(Kc + aK1 + c * 4096 + t * 512);
        f32x4 z = {};
        z = MFMA16(kf0, qA0, z);
        z = MFMA16(kf1, qA1, z);
        sT[c][t] = z;
      }
    __builtin_amdgcn_s_setprio(0);
    softmax_tile(sT, kb, qw, r, half, mA, lA, omA, pwA);
    // ---- q-group B ----
    __builtin_amdgcn_s_setprio(1);
#pragma unroll
    for (int c = 0; c < 2; ++c)
#pragma unroll
      for (int t = 0; t < 2; ++t) {
        const bf16x8 kf0 = *(const bf16x8*)(Kc + aK0 + c * 4096 + t * 512);
        const bf16x8 kf1 = *(const bf16x8*)(Kc + aK1 + c * 4096 + t * 512);
        f32x4 z = {};
        z = MFMA16(kf0, qB0, z);
        z = MFMA16(kf1, qB1, z);
        sT[c][t] = z;
      }
    __builtin_amdgcn_s_setprio(0);
    softmax_tile(sT, kb, qw + 16, r, half, mB, lB, omB, pwB);
    // ---- PV (V frags shared across both groups) ----
    __builtin_amdgcn_s_setprio(1);
#pragma unroll
    for (int c = 0; c < 2; ++c) {
      const bf16x8 pa = __builtin_bit_cast(bf16x8, pwA[c]);
      const bf16x8 pb = __builtin_bit_cast(bf16x8, pwB[c]);
      const int av = c ? aV1 : aV0;
#pragma unroll
      for (int f = 0; f < 4; ++f) {
        const bf16x8 vf = *(const bf16x8*)(Vc + av + f * 2048);
        omA[f] = MFMA16(vf, pa, omA[f]);
        omB[f] = MFMA16(vf, pb, omB[f]);
      }
    }
    __builtin_amdgcn_s_setprio(0);
    cur ^= 4096;
  }

  // one cross-replica l-reduce per strip
  lA += __shfl_xor(lA, 16); lA += __shfl_xor(lA, 32);
  lB += __shfl_xor(lB, 16); lB += __shfl_xor(lB, 32);
  const float invA = 1.0f / lA;
  const float invB = 1.0f / lB;
  const int qa = qw + r, qb2 = qw + 16 + r;
#pragma unroll
  for (int f = 0; f < 4; ++f) {
    ushort4 sa, sb;
    sa.x = f2b(omA[f][0] * invA); sa.y = f2b(omA[f][1] * invA);
    sa.z = f2b(omA[f][2] * invA); sa.w = f2b(omA[f][3] * invA);
    sb.x = f2b(omB[f][0] * invB); sb.y = f2b(omB[f][1] * invB);
    sb.z = f2b(omB[f][2] * invB); sb.w = f2b(omB[f][3] * invB);
    *(ushort4*)&Zb[(size_t)qa * 64 + f * 16 + half * 4] = sa;
    *(ushort4*)&Zb[(size_t)qb2 * 64 + f * 16 + half * 4] = sb;
  }
}

__global__ __launch_bounds__(128, 4) void attn_kernel(
    const u16* __restrict__ Q, const u16* __restrict__ K,
    const u16* __restrict__ Vt, u16* __restrict__ Z) {
  __shared__ u16 Kl[2][4096];
  __shared__ u16 Vl[2][4096];
  // XCD-affinity: all q-strip-pairs of a head on one XCD (round-robin linear%8)
  const int L = blockIdx.x;
  const int xcd = L & 7;
  const int i = L >> 3;
  const int bh = ((i >> 4) << 3) | xcd;   // heads with bh%8 == xcd
  const int x = i & 15;                   // strip-pair index
  const int tid = threadIdx.x;
  const u16* Qb = Q + (size_t)bh * 131072;
  const u16* Kb = K + (size_t)bh * 131072;
  const u16* Vtb = Vt + (size_t)bh * 131072;
  u16* Zb = Z + (size_t)bh * 131072;
  attn_strip32(Qb, Kb, Vtb, Zb, &Kl[0][0], &Vl[0][0], x * 64, x + 1, tid);
  attn_strip32(Qb, Kb, Vtb, Zb, &Kl[0][0], &Vl[0][0], (31 - x) * 64, 32 - x, tid);
}

extern "C" void kernel_launch(void* const* d_in, const int* in_sizes, int n_in,
                              void* d_out, int out_size, void* d_ws, size_t ws_size,
                              hipStream_t stream) {
  (void)in_sizes; (void)n_in; (void)out_size; (void)ws_size;
  const float* x  = (const float*)d_in[0];
  const float* Wq = (const float*)d_in[1];
  const float* bq = (const float*)d_in[2];
  const float* Wk = (const float*)d_in[3];
  const float* bk = (const float*)d_in[4];
  const float* Wv = (const float*)d_in[5];
  const float* bv = (const float*)d_in[6];
  const float* Wo = (const float*)d_in[7];
  const float* bo = (const float*)d_in[8];
  float* out = (float*)d_out;

  char* ws = (char*)d_ws;
  u16* xb  = (u16*)(ws);                  // 16 MB, reused as Z after attention
  u16* Wts = (u16*)(ws + 16777216);       // 4 x 2 MB (q,k,v,o; n-major bf16)
  u16* Qb  = (u16*)(ws + 25165824);       // 16 MB
  u16* Kb  = (u16*)(ws + 41943040);       // 16 MB
  u16* Vb  = (u16*)(ws + 58720256);       // 16 MB
  u16* Vtb = (u16*)(ws + 75497472);       // 16 MB  (total 92 MB)

  convert_f32_bf16<<<4096, 256, 0, stream>>>(x, xb);
  {
    dim3 g(32, 32, 4), b(32, 8);
    transpose_convert_w<<<g, b, 0, stream>>>(Wq, Wk, Wv, Wo, Wts);
  }
  {
    dim3 g(64, 8, 3), b(256);
    gemm_kernel<false><<<g, b, 0, stream>>>(xb, Wts, bq, bk, bv, Qb, nullptr);
  }
  {
    dim3 g(64, 2, 64), b(32, 8);
    transpose_v<<<g, b, 0, stream>>>(Vb, Vtb);
  }
  {
    dim3 g(1024), b(128);
    attn_kernel<<<g, b, 0, stream>>>(Qb, Kb, Vtb, xb /* Z */);
  }
  {
    dim3 g(64, 8, 1), b(256);
    gemm_kernel<true><<<g, b, 0, stream>>>(xb, Wts + 3 * 1048576, bo, bo, bo, Qb, out);
  }
}